// Round 12
// baseline (118.595 us; speedup 1.0000x reference)
//
#include <hip/hip_runtime.h>
#include <stdint.h>

#define N_ANCH 4096
#define NCLS 8
#define CN (N_ANCH * NCLS)
#define SCORE_TH 0.5f
#define IOU_TH 0.5f
#define KSEL 11
#define MAX_DET 100
#define CAND_CAP 4096
#define TI 256                        // i-rows per block (2 rows/thread)
#define TJ 64                         // j-cols per block (LDS-staged)
#define JOBS_PER_CLASS 544            // sum_{ci=0}^{15} (4*ci+4) = 2*16*17

struct Params {
    const float* boxes; const float* cls; const float* poses; const float* conf;
    int* validList; int* mVal; int* minRank;
    int* surv; int* hist; int* blockCnt; int* gcnt;
    int* rep; int* sel; int* count_g; float* cand;
    float* out;
};

__device__ __forceinline__ float area_f(float4 b) {
    return (b.z - b.x + 1.0f) * (b.w - b.y + 1.0f);
}

__device__ __forceinline__ float iou_f(float4 a, float areaA, float4 b, float areaB) {
    float x1 = fmaxf(a.x, b.x);
    float y1 = fmaxf(a.y, b.y);
    float x2 = fminf(a.z, b.z);
    float y2 = fminf(a.w, b.w);
    float wid = x2 - x1 + 1.0f;
    float hei = y2 - y1 + 1.0f;
    float inter = wid * hei;
    float den = areaA + areaB - inter;
    float ov = (den == 0.0f) ? 0.0f : (inter / den);
    if (wid <= 0.0f || hei <= 0.0f) ov = 0.0f;
    return ov;
}

// kS: 8 blocks (one per class). Single-pass ordered valid-list build
// (ballot all 16 chunks -> LDS, one-thread prefix, scatter) + all zero-init
// (surv, minRank=INF, rep=-1, hist, blockCnt, gcnt).
__global__ void __launch_bounds__(256) kS(Params p) {
    const int c = blockIdx.x;
    const int tid = threadIdx.x;
    const int lane = tid & 63, w = tid >> 6;
    const int cbase = c << 12;
    __shared__ unsigned long long smask[64];  // [16][4]
    __shared__ int sbase[16];

    for (int ch = 0; ch < 16; ch++) {
        int n = ch * 256 + tid;
        int flag = (p.cls[n * 8 + c] > SCORE_TH) ? 1 : 0;
        unsigned long long m = __ballot(flag);
        if (lane == 0) smask[ch * 4 + w] = m;
    }
    __syncthreads();
    if (tid == 0) {
        int run = 0;
        for (int ch = 0; ch < 16; ch++) {
            sbase[ch] = run;
            run += __popcll(smask[ch * 4]) + __popcll(smask[ch * 4 + 1]) +
                   __popcll(smask[ch * 4 + 2]) + __popcll(smask[ch * 4 + 3]);
        }
        p.mVal[c] = run;
    }
    __syncthreads();
    for (int ch = 0; ch < 16; ch++) {
        unsigned long long m = smask[ch * 4 + w];
        if ((m >> lane) & 1ull) {
            int rank = __popcll(m & ((1ull << lane) - 1ull));
            int wb = 0;
            for (int i = 0; i < w; i++) wb += __popcll(smask[ch * 4 + i]);
            p.validList[c * N_ANCH + sbase[ch] + wb + rank] = ch * 256 + tid;
        }
    }
    for (int i = tid; i < N_ANCH; i += 256) {
        p.surv[cbase + i] = 0;
        p.minRank[cbase + i] = 0x7FFFFFFF;
        p.rep[cbase + i] = -1;   // invalid anchors never match rep==r tests
    }
    if (c == 0) {
        for (int i = tid; i < 1024; i += 256) p.hist[i] = 0;
        if (tid < 128) p.blockCnt[tid] = 0;
        if (tid == 0) *p.gcnt = 0;
    }
}

// kM: rep-matrix min-rank scan, 2 rows per thread. Block = (class, i-tile of
// 256 rows, j-tile of 64 cols, triangular: jb < ib+TI). Each sB[r] read feeds
// two IoU chains (half the LDS traffic, double the ILP). Division-free
// IoU>0.5 predicate (inter > 0.5*den). Masked limits handle the diagonal.
__global__ void __launch_bounds__(128) kM(Params p) {
    int bid = blockIdx.x;
    int c = bid / JOBS_PER_CLASS;
    int t = bid - c * JOBS_PER_CLASS;
    // off(ci) = 2*ci*(ci+1); ci has 4*ci+4 j-tiles
    int ci = (int)((sqrtf(2.0f * (float)t + 1.0f) - 1.0f) * 0.5f);
    while (2 * (ci + 1) * (ci + 2) <= t) ci++;
    while (2 * ci * (ci + 1) > t) ci--;
    int jt = t - 2 * ci * (ci + 1);          // jt in [0, 4*ci+3]
    int mc = p.mVal[c];
    int ib = ci * TI, jb = jt * TJ;
    if (ib >= mc || jb >= mc) return;
    int tid = threadIdx.x;
    int cbase = c << 12;
    const int* vl = p.validList + cbase;
    const float4* boxes4 = (const float4*)p.boxes;
    __shared__ float4 sB[TJ];
    __shared__ float sA[TJ];
    if (tid < TJ && jb + tid < mc) {
        int vj = vl[jb + tid];
        float4 b = boxes4[vj * 8 + c];
        sB[tid] = b;
        sA[tid] = area_f(b);
    }
    __syncthreads();
    int i1 = ib + tid;
    int i2 = i1 + 128;
    if (i1 >= mc) return;                // then i2 >= mc too; past last barrier
    bool h2 = i2 < mc;
    int limU = min(TJ, mc - jb);
    int lim1 = min(limU, max(0, i1 - jb));
    int lim2 = h2 ? min(limU, i2 - jb) : 0;   // lim2 >= lim1 when h2
    int lmax = max(lim1, lim2);
    if (lmax <= 0) return;
    int k1 = vl[i1];
    int k2 = h2 ? vl[i2] : k1;           // guard: vl beyond mc is garbage
    float4 b1 = boxes4[k1 * 8 + c];
    float a1 = area_f(b1);
    float4 b2 = boxes4[k2 * 8 + c];
    float a2 = area_f(b2);
    int lmin1 = 0x7FFFFFFF, lmin2 = 0x7FFFFFFF;
    #pragma unroll 4
    for (int r = 0; r < lmax; r++) {
        float4 bj = sB[r];
        float aj = sA[r];
        // row 1
        float x1a = fmaxf(b1.x, bj.x), y1a = fmaxf(b1.y, bj.y);
        float x2a = fminf(b1.z, bj.z), y2a = fminf(b1.w, bj.w);
        float wa = x2a - x1a + 1.0f, ha = y2a - y1a + 1.0f;
        float ia = wa * ha;
        float da = a1 + aj - ia;
        bool m1 = (wa > 0.0f) && (ha > 0.0f) && (ia > 0.5f * da) && (r < lim1);
        if (m1 && r < lmin1) lmin1 = r;
        // row 2
        float x1b = fmaxf(b2.x, bj.x), y1b = fmaxf(b2.y, bj.y);
        float x2b = fminf(b2.z, bj.z), y2b = fminf(b2.w, bj.w);
        float wb = x2b - x1b + 1.0f, hb = y2b - y1b + 1.0f;
        float ib2 = wb * hb;
        float db = a2 + aj - ib2;
        bool m2 = (wb > 0.0f) && (hb > 0.0f) && (ib2 > 0.5f * db) && (r < lim2);
        if (m2 && r < lmin2) lmin2 = r;
    }
    if (lmin1 != 0x7FFFFFFF) atomicMin(&p.minRank[cbase + i1], jb + lmin1);
    if (h2 && lmin2 != 0x7FFFFFFF) atomicMin(&p.minRank[cbase + i2], jb + lmin2);
}

// kF: finalize rep + surv (first-setter also bumps blockCnt + score hist).
__global__ void __launch_bounds__(256) kF(Params p) {
    int t = blockIdx.x * 256 + threadIdx.x;
    int c = t >> 12;
    int i = t & (N_ANCH - 1);   // rank
    if (i >= p.mVal[c]) return;
    int cbase = c << 12;
    const int* vl = p.validList + cbase;
    const float4* boxes4 = (const float4*)p.boxes;
    int k = vl[i];
    int mr = p.minRank[t];
    if (mr > i) mr = i;         // self
    int ja = vl[mr];
    p.rep[cbase + k] = ja;
    if (mr < i) {
        float4 bk = boxes4[k * 8 + c];
        float4 bj = boxes4[ja * 8 + c];
        float ov = iou_f(bk, area_f(bk), bj, area_f(bj));
        float bcv = (1.0f - ov) * p.conf[k * 8 + c];
        if (bcv != 0.0f) {
            int old = atomicExch(&p.surv[cbase + ja], 1);
            if (old == 0) {
                atomicAdd(&p.blockCnt[(cbase + ja) >> 8], 1);
                unsigned bits = __float_as_uint(p.cls[ja * 8 + c]);
                int bb = (int)((bits - 0x3F000000u) >> 13);
                int bkt = bb < 0 ? 0 : (bb > 1023 ? 1023 : bb);
                atomicAdd(&p.hist[bkt], 1);
            }
        }
    }
}

// kG: 128 blocks. Redundant chunk-prefix + histogram threshold, ordered
// sel-write of first 100 survivors (flat order), candidate score gather.
__global__ void __launch_bounds__(256) kG(Params p) {
    const int bid = blockIdx.x;
    const int tid = threadIdx.x;
    const int lane = tid & 63, w = tid >> 6;
    __shared__ int sCnt[128];
    __shared__ int sSfx[256];
    __shared__ int s_misc[8];

    if (tid == 0) s_misc[0] = 0;  // thrB
    if (tid < 128) sCnt[tid] = p.blockCnt[tid];
    int part = p.hist[4 * tid] + p.hist[4 * tid + 1] +
               p.hist[4 * tid + 2] + p.hist[4 * tid + 3];
    sSfx[tid] = part;
    __syncthreads();
    if (tid == 0) {
        int run = 0, myoff = 0;
        for (int i = 0; i < 128; i++) {
            if (i == bid) myoff = run;
            run += sCnt[i];
        }
        s_misc[1] = run;    // total survivor count
        s_misc[2] = myoff;  // this chunk's base offset
        if (bid == 0) *p.count_g = run;
        int run2 = 0;
        for (int i = 255; i >= 0; i--) { int v = sSfx[i]; sSfx[i] = run2; run2 += v; }
    }
    __syncthreads();
    int count = s_misc[1];
    int target = count < MAX_DET ? count : MAX_DET;
    int S = sSfx[tid];
    int found = -1;
    for (int b = 4 * tid + 3; b >= 4 * tid; b--) {
        S += p.hist[b];
        if (found < 0 && S >= target) found = b;
    }
    if (found >= 0) atomicMax(&s_misc[0], found);
    __syncthreads();
    int t0 = s_misc[0];

    // ordered gather
    int q = bid * 256 + tid;
    int c = q >> 12, n = q & (N_ANCH - 1);
    int flag = p.surv[q] != 0;
    unsigned long long mask = __ballot(flag);
    if (lane == 0) s_misc[4 + w] = __popcll(mask);
    __syncthreads();
    int rank = __popcll(mask & ((1ull << lane) - 1ull));
    int wbase = 0;
    for (int i = 0; i < w; i++) wbase += s_misc[4 + i];
    int idx = s_misc[2] + wbase + rank;
    if (flag && idx < MAX_DET) p.sel[idx] = q;
    if (flag) {
        float sc = p.cls[n * 8 + c];
        unsigned bits = __float_as_uint(sc);
        int bb = (int)((bits - 0x3F000000u) >> 13);
        int bkt = bb < 0 ? 0 : (bb > 1023 ? 1023 : bb);
        if (bkt >= t0) {
            int id = atomicAdd(p.gcnt, 1);
            if (id < CAND_CAP) p.cand[id] = sc;
        }
    }
}

// kO: block 0 = bitonic sort of candidate scores -> top-100 scores;
// blocks 1..100 = per-slot cluster gather (rep==r only; rep=-1 for invalid)
// + KSEL selection + averages.
__global__ void __launch_bounds__(256) kO(Params p) {
    const int bid = blockIdx.x;
    const int tid = threadIdx.x;
    const int lane = tid & 63, w = tid >> 6;
    __shared__ __align__(16) unsigned char SMEM[32768];
    __shared__ int s_misc[8];
    __shared__ int s_ksel[KSEL];
    __shared__ unsigned long long s_red[5];
    const float4* boxes4 = (const float4*)p.boxes;

    if (bid == 0) {
        float* s = (float*)SMEM;
        int cc = *p.gcnt; if (cc > CAND_CAP) cc = CAND_CAP;
        int count = *p.count_g;
        int n = 128; while (n < cc) n <<= 1;
        for (int i = tid; i < n; i += 256) s[i] = (i < cc) ? -p.cand[i] : 1e38f;
        __syncthreads();
        for (int kk = 2; kk <= n; kk <<= 1) {
            for (int jj = kk >> 1; jj > 0; jj >>= 1) {
                for (int i = tid; i < n; i += 256) {
                    int ixj = i ^ jj;
                    if (ixj > i) {
                        float a = s[i], b2 = s[ixj];
                        bool up = ((i & kk) == 0);
                        if (up ? (a > b2) : (a < b2)) { s[i] = b2; s[ixj] = a; }
                    }
                }
                __syncthreads();
            }
        }
        if (tid < MAX_DET) p.out[tid] = (tid < count) ? -s[tid] : -1.0f;
    } else {
        int s = bid - 1;
        int count = *p.count_g;
        if (s >= count) {
            if (tid == 0) { p.out[100 + s] = -1.0f; p.out[1400 + s] = -1.0f; }
            if (tid < 12) p.out[200 + s * 12 + tid] = -1.0f;
            if (tid >= 16 && tid < 20) p.out[1500 + s * 4 + (tid - 16)] = -1.0f;
        } else {
            int sp = p.sel[s];
            int c = sp >> 12;
            int r = sp & (N_ANCH - 1);
            int cbase = c << 12;
            unsigned long long* keyArr = (unsigned long long*)SMEM;  // 4096 x 8 B
            if (tid == 0) s_misc[0] = 0;  // nm
            __syncthreads();
            float4 br = boxes4[r * 8 + c];
            float ar = area_f(br);
            for (int k = tid; k < N_ANCH; k += 256) {
                if (k != r && p.rep[cbase + k] == r) {     // rep=-1 for invalid
                    float4 bkk = boxes4[k * 8 + c];
                    float ov = iou_f(br, ar, bkk, area_f(bkk));
                    float bcv = (1.0f - ov) * p.conf[k * 8 + c];
                    if (bcv != 0.0f) {
                        int id = atomicAdd(&s_misc[0], 1);
                        keyArr[id] = ((unsigned long long)__float_as_uint(bcv) << 32) | (unsigned)k;
                    }
                }
            }
            __syncthreads();
            int nm = s_misc[0];
            int dn = nm < KSEL ? nm : KSEL;
            unsigned long long lastBest = ~0ull;
            for (int j = 0; j < dn; j++) {
                unsigned long long bk = ~0ull;
                for (int i = tid; i < nm; i += 256) {
                    unsigned long long v = keyArr[i];
                    if (v == lastBest) { keyArr[i] = ~0ull; v = ~0ull; }
                    if (v < bk) bk = v;
                }
                for (int off = 32; off > 0; off >>= 1) {
                    unsigned long long o = __shfl_down(bk, off);
                    if (o < bk) bk = o;
                }
                if (lane == 0) s_red[w] = bk;
                __syncthreads();
                if (tid == 0) {
                    unsigned long long B = s_red[0];
                    for (int q2 = 1; q2 < 4; q2++) if (s_red[q2] < B) B = s_red[q2];
                    s_red[4] = B;
                    s_ksel[j] = (int)(B & 0xFFFFFFFFull);
                }
                __syncthreads();
                lastBest = s_red[4];
            }
            float fdn = (float)(dn > 0 ? dn : 1);
            if (tid < 12) {
                float ssum = 0.0f;
                for (int j = 0; j < dn; j++) {
                    int k = s_ksel[j];
                    ssum += p.poses[(k * 8 + c) * 12 + tid];
                }
                p.out[200 + s * 12 + tid] = ssum / fdn;
            } else if (tid < 16) {
                int d = tid - 12;
                float ssum = 0.0f;
                for (int j = 0; j < dn; j++) {
                    int k = s_ksel[j];
                    const float* bb2 = (const float*)&boxes4[k * 8 + c];
                    ssum += bb2[d];
                }
                p.out[1500 + s * 4 + d] = ssum / fdn;
            } else if (tid == 16) {
                p.out[100 + s] = (float)c;
            } else if (tid == 17) {
                p.out[1400 + s] = (float)r;
            }
        }
    }
}

extern "C" void kernel_launch(void* const* d_in, const int* in_sizes, int n_in,
                              void* d_out, int out_size, void* d_ws, size_t ws_size,
                              hipStream_t stream) {
    Params hp;
    hp.boxes = (const float*)d_in[1];
    hp.cls   = (const float*)d_in[2];
    hp.poses = (const float*)d_in[3];
    hp.conf  = (const float*)d_in[4];
    hp.out   = (float*)d_out;

    char* ws = (char*)d_ws;
    size_t off = 0;
    auto alloc = [&](size_t bytes) {
        void* pp = ws + off;
        off += (bytes + 255) & ~(size_t)255;
        return pp;
    };
    hp.validList = (int*)alloc(CN * sizeof(int));
    hp.mVal      = (int*)alloc(64);
    hp.minRank   = (int*)alloc(CN * sizeof(int));
    hp.surv      = (int*)alloc(CN * sizeof(int));
    hp.hist      = (int*)alloc(1024 * sizeof(int));
    hp.blockCnt  = (int*)alloc(128 * sizeof(int));
    hp.gcnt      = (int*)alloc(64);
    hp.rep       = (int*)alloc(CN * sizeof(int));
    hp.sel       = (int*)alloc(MAX_DET * sizeof(int));
    hp.count_g   = (int*)alloc(64);
    hp.cand      = (float*)alloc(CAND_CAP * sizeof(float));

    kS<<<NCLS, 256, 0, stream>>>(hp);                    // 8 blocks
    kM<<<NCLS * JOBS_PER_CLASS, 128, 0, stream>>>(hp);   // 4352 blocks
    kF<<<CN / 256, 256, 0, stream>>>(hp);                // 128 blocks
    kG<<<CN / 256, 256, 0, stream>>>(hp);                // 128 blocks
    kO<<<MAX_DET + 1, 256, 0, stream>>>(hp);             // 101 blocks
}